// Round 3
// baseline (508.520 us; speedup 1.0000x reference)
//
#include <hip/hip_runtime.h>
#include <stdint.h>

// Problem constants (fixed by reference)
#define NB 8
#define NH 12
#define NLQ 32
#define NLF 256
#define NV 32000
#define NS 4
#define NV4 (NV / 4)   /* 8000 float4 per [b] row */

// d_out layout: values[NS,NB,NV] | logprobs[NS,NB] | actions[NS,NB,NLF]
#define OUT_LOGP (NS * NB * NV)          /* 1024000 */
#define OUT_ACT  (OUT_LOGP + NS * NB)    /* 1024032 */

__device__ __forceinline__ uint32_t rotl32(uint32_t v, int r) {
  return (v << r) | (v >> (32 - r));
}

// Exact JAX threefry2x32 (rotations [13,15,26,6]/[17,29,16,24], 5 key injections)
__device__ __forceinline__ void threefry2x32(uint32_t k0, uint32_t k1,
                                             uint32_t& x0, uint32_t& x1) {
  const uint32_t ks2 = k0 ^ k1 ^ 0x1BD11BDAu;
  x0 += k0; x1 += k1;
#define TF_ROUND(r) { x0 += x1; x1 = rotl32(x1, r); x1 ^= x0; }
  TF_ROUND(13) TF_ROUND(15) TF_ROUND(26) TF_ROUND(6)
  x0 += k1; x1 += ks2 + 1u;
  TF_ROUND(17) TF_ROUND(29) TF_ROUND(16) TF_ROUND(24)
  x0 += ks2; x1 += k0 + 2u;
  TF_ROUND(13) TF_ROUND(15) TF_ROUND(26) TF_ROUND(6)
  x0 += k0; x1 += k1 + 3u;
  TF_ROUND(17) TF_ROUND(29) TF_ROUND(16) TF_ROUND(24)
  x0 += k1; x1 += ks2 + 4u;
  TF_ROUND(13) TF_ROUND(15) TF_ROUND(26) TF_ROUND(6)
  x0 += ks2; x1 += k0 + 5u;
#undef TF_ROUND
}

// ---------- Kernel 1: mean over heads -> ws_scores[B,LQ,LF] ----------
// 256 blocks so the 3 MB read spreads over all CUs (a fused 8-block version
// would pull it through 8 CUs at ~20x lower aggregate BW).
__global__ __launch_bounds__(256) void k_mean(const float* __restrict__ as,
                                              float* __restrict__ scores) {
  const int o = blockIdx.x * 256 + threadIdx.x;   // [0, 65536)
  const int f  = o & (NLF - 1);
  const int lq = (o >> 8) & (NLQ - 1);
  const int b  = o >> 13;
  float s = 0.f;
#pragma unroll
  for (int h = 0; h < NH; ++h)
    s += as[(((size_t)(b * NH + h) * NLQ) + lq) * NLF + f];
  scores[o] = s / 12.0f;
}

// ---------- Kernel 2: probs, threefry actions, logprobs ----------
// grid = NB blocks, 256 threads (one per f); reads 256 KB (L2/L3-hot)
__global__ __launch_bounds__(256) void k_probs(
    const float* __restrict__ scores,      // ws [B,LQ,LF]
    const float* __restrict__ attn_mask,   // [B,LF]
    float* __restrict__ out,               // d_out base
    unsigned* __restrict__ actmask)        // ws [B,LF], bit s = action[s,b,f]
{
  const int b = blockIdx.x;
  const int f = threadIdx.x;

  float agg = -INFINITY;
#pragma unroll
  for (int lq = 0; lq < NLQ; ++lq)
    agg = fmaxf(agg, scores[(b * NLQ + lq) * NLF + f]);

  const float amask = attn_mask[b * NLF + f];
  const float p = amask * (1.0f / (1.0f + expf(-agg)));   // sigmoid * mask

  const float lp  = logf(p);       // used only when action==1 (p>0 then)
  const float l1p = log1pf(-p);

  unsigned mask = 0;
  float terms[NS];
#pragma unroll
  for (int s = 0; s < NS; ++s) {
    bool act;
    if (s < NS - 1) {
      // JAX partitionable threefry 32-bit bits: counter n (u64),
      // (o0,o1) = threefry2x32(key, hi(n)=0, lo(n)=n); bits = o0 ^ o1
      const uint32_t n = (uint32_t)(s * (NB * NLF) + b * NLF + f);
      uint32_t x0 = 0u, x1 = n;
      threefry2x32(0u, 42u, x0, x1);
      const uint32_t bits = x0 ^ x1;
      const float u = __uint_as_float((bits >> 9) | 0x3f800000u) - 1.0f;
      act = (u < p);
    } else {
      act = (p >= 0.5f);
    }
    if (act) mask |= (1u << s);
    terms[s] = act ? lp : l1p;
    out[OUT_ACT + (s * NB + b) * NLF + f] = act ? 1.0f : 0.0f;
  }
  actmask[b * NLF + f] = mask;

  // block-reduce logprob terms over f for each s
  __shared__ float red[NS][NLF];
#pragma unroll
  for (int s = 0; s < NS; ++s) red[s][f] = terms[s];
  __syncthreads();
  for (int off = 128; off > 0; off >>= 1) {
    if (f < off) {
#pragma unroll
      for (int s = 0; s < NS; ++s) red[s][f] += red[s][f + off];
    }
    __syncthreads();
  }
  if (f == 0) {
#pragma unroll
    for (int s = 0; s < NS; ++s) out[OUT_LOGP + s * NB + b] = red[s][0];
  }
}

// ---------- Kernel 3: values[s,b,v] ----------
// grid = (32, NB), 256 threads; each thread owns one float4 (16 B/lane —
// the coalescing sweet spot). Memory-bound: 295 MB read, ~48 us floor.
__global__ __launch_bounds__(256) void k_values(
    const float* __restrict__ q_logits,   // [B,LQ,V]
    const float* __restrict__ f_logits,   // [B,LF,V]
    const float* __restrict__ q_mask,     // [B,LQ]
    const unsigned* __restrict__ actmask, // ws [B,LF]
    float* __restrict__ out)              // d_out base (values at offset 0)
{
  const int b = blockIdx.y;
  const int tid = threadIdx.x;

  __shared__ unsigned smask[NLF];
  __shared__ float sqmask[NLQ];
  smask[tid] = actmask[b * NLF + tid];
  if (tid < NLQ) sqmask[tid] = q_mask[b * NLQ + tid];
  __syncthreads();

  const int c4 = blockIdx.x * 256 + tid;      // float4 index within row
  if (c4 >= NV4) return;

  const float4* qp = (const float4*)q_logits;
  const float4* fp = (const float4*)f_logits;

  // q_max = max_lq log1p(relu(q)) * q_mask  (general mask: per-element)
  float q0 = -INFINITY, q1 = -INFINITY, q2 = -INFINITY, q3 = -INFINITY;
#pragma unroll 8
  for (int lq = 0; lq < NLQ; ++lq) {
    const float4 x = qp[(size_t)(b * NLQ + lq) * NV4 + c4];
    const float qm = sqmask[lq];
    q0 = fmaxf(q0, log1pf(fmaxf(x.x, 0.f)) * qm);
    q1 = fmaxf(q1, log1pf(fmaxf(x.y, 0.f)) * qm);
    q2 = fmaxf(q2, log1pf(fmaxf(x.z, 0.f)) * qm);
    q3 = fmaxf(q3, log1pf(fmaxf(x.w, 0.f)) * qm);
  }

  // masked raw-max over f for each sample (log1p applied once at the end;
  // valid because log1p(relu(.)) is monotone and am in {0,1} for this input)
  float m[NS][4];
#pragma unroll
  for (int s = 0; s < NS; ++s)
#pragma unroll
    for (int c = 0; c < 4; ++c) m[s][c] = -INFINITY;

#pragma unroll 8
  for (int f = 0; f < NLF; ++f) {
    const float4 x = fp[(size_t)(b * NLF + f) * NV4 + c4];
    const unsigned mk = smask[f];   // block-uniform -> scalar branch, skips work
    if (mk & 1u) { m[0][0] = fmaxf(m[0][0], x.x); m[0][1] = fmaxf(m[0][1], x.y);
                   m[0][2] = fmaxf(m[0][2], x.z); m[0][3] = fmaxf(m[0][3], x.w); }
    if (mk & 2u) { m[1][0] = fmaxf(m[1][0], x.x); m[1][1] = fmaxf(m[1][1], x.y);
                   m[1][2] = fmaxf(m[1][2], x.z); m[1][3] = fmaxf(m[1][3], x.w); }
    if (mk & 4u) { m[2][0] = fmaxf(m[2][0], x.x); m[2][1] = fmaxf(m[2][1], x.y);
                   m[2][2] = fmaxf(m[2][2], x.z); m[2][3] = fmaxf(m[2][3], x.w); }
    if (mk & 8u) { m[3][0] = fmaxf(m[3][0], x.x); m[3][1] = fmaxf(m[3][1], x.y);
                   m[3][2] = fmaxf(m[3][2], x.z); m[3][3] = fmaxf(m[3][3], x.w); }
  }

  float4* ov = (float4*)out;
#pragma unroll
  for (int s = 0; s < NS; ++s) {
    float4 r;
    r.x = fmaxf(q0, log1pf(fmaxf(m[s][0], 0.f)));
    r.y = fmaxf(q1, log1pf(fmaxf(m[s][1], 0.f)));
    r.z = fmaxf(q2, log1pf(fmaxf(m[s][2], 0.f)));
    r.w = fmaxf(q3, log1pf(fmaxf(m[s][3], 0.f)));
    ov[(size_t)(s * NB + b) * NV4 + c4] = r;
  }
}

extern "C" void kernel_launch(void* const* d_in, const int* in_sizes, int n_in,
                              void* d_out, int out_size, void* d_ws, size_t ws_size,
                              hipStream_t stream) {
  const float* attn_scores = (const float*)d_in[0];
  const float* q_logits    = (const float*)d_in[1];
  const float* f_logits    = (const float*)d_in[2];
  const float* q_mask      = (const float*)d_in[3];
  const float* attn_mask   = (const float*)d_in[4];
  float* out = (float*)d_out;

  float* ws_scores   = (float*)d_ws;                         // B*LQ*LF floats
  unsigned* ws_mask  = (unsigned*)(ws_scores + NB * NLQ * NLF); // B*LF uint32

  k_mean<<<dim3((NB * NLQ * NLF) / 256), 256, 0, stream>>>(attn_scores, ws_scores);
  k_probs<<<dim3(NB), 256, 0, stream>>>(ws_scores, attn_mask, out, ws_mask);
  k_values<<<dim3((NV4 + 255) / 256, NB), 256, 0, stream>>>(
      q_logits, f_logits, q_mask, ws_mask, out);
}

// Round 4
// 389.033 us; speedup vs baseline: 1.3071x; 1.3071x over previous
//
#include <hip/hip_runtime.h>
#include <stdint.h>

// Problem constants (fixed by reference)
#define NB 8
#define NH 12
#define NLQ 32
#define NLF 256
#define NV 32000
#define NS 4
#define NV4 (NV / 4)   /* 8000 float4 per [b] row */

// d_out layout: values[NS,NB,NV] | logprobs[NS,NB] | actions[NS,NB,NLF]
#define OUT_LOGP (NS * NB * NV)          /* 1024000 */
#define OUT_ACT  (OUT_LOGP + NS * NB)    /* 1024032 */

__device__ __forceinline__ uint32_t rotl32(uint32_t v, int r) {
  return (v << r) | (v >> (32 - r));
}

// Exact JAX threefry2x32 (rotations [13,15,26,6]/[17,29,16,24], 5 key injections)
__device__ __forceinline__ void threefry2x32(uint32_t k0, uint32_t k1,
                                             uint32_t& x0, uint32_t& x1) {
  const uint32_t ks2 = k0 ^ k1 ^ 0x1BD11BDAu;
  x0 += k0; x1 += k1;
#define TF_ROUND(r) { x0 += x1; x1 = rotl32(x1, r); x1 ^= x0; }
  TF_ROUND(13) TF_ROUND(15) TF_ROUND(26) TF_ROUND(6)
  x0 += k1; x1 += ks2 + 1u;
  TF_ROUND(17) TF_ROUND(29) TF_ROUND(16) TF_ROUND(24)
  x0 += ks2; x1 += k0 + 2u;
  TF_ROUND(13) TF_ROUND(15) TF_ROUND(26) TF_ROUND(6)
  x0 += k0; x1 += k1 + 3u;
  TF_ROUND(17) TF_ROUND(29) TF_ROUND(16) TF_ROUND(24)
  x0 += k1; x1 += ks2 + 4u;
  TF_ROUND(13) TF_ROUND(15) TF_ROUND(26) TF_ROUND(6)
  x0 += ks2; x1 += k0 + 5u;
#undef TF_ROUND
}

// ---------- Kernel 1: mean over heads -> ws_scores[B,LQ,LF] ----------
__global__ __launch_bounds__(256) void k_mean(const float* __restrict__ as,
                                              float* __restrict__ scores) {
  const int o = blockIdx.x * 256 + threadIdx.x;   // [0, 65536)
  const int f  = o & (NLF - 1);
  const int lq = (o >> 8) & (NLQ - 1);
  const int b  = o >> 13;
  float s = 0.f;
#pragma unroll
  for (int h = 0; h < NH; ++h)
    s += as[(((size_t)(b * NH + h) * NLQ) + lq) * NLF + f];
  scores[o] = s / 12.0f;
}

// ---------- Kernel 2: probs, threefry actions, logprobs ----------
__global__ __launch_bounds__(256) void k_probs(
    const float* __restrict__ scores,      // ws [B,LQ,LF]
    const float* __restrict__ attn_mask,   // [B,LF]
    float* __restrict__ out,               // d_out base
    unsigned* __restrict__ actmask)        // ws [B,LF], bit s = action[s,b,f]
{
  const int b = blockIdx.x;
  const int f = threadIdx.x;

  float agg = -INFINITY;
#pragma unroll
  for (int lq = 0; lq < NLQ; ++lq)
    agg = fmaxf(agg, scores[(b * NLQ + lq) * NLF + f]);

  const float amask = attn_mask[b * NLF + f];
  const float p = amask * (1.0f / (1.0f + expf(-agg)));   // sigmoid * mask

  const float lp  = logf(p);       // used only when action==1 (p>0 then)
  const float l1p = log1pf(-p);

  unsigned mask = 0;
  float terms[NS];
#pragma unroll
  for (int s = 0; s < NS; ++s) {
    bool act;
    if (s < NS - 1) {
      // JAX partitionable threefry 32-bit bits: counter n (u64),
      // (o0,o1) = threefry2x32(key, hi(n)=0, lo(n)=n); bits = o0 ^ o1
      const uint32_t n = (uint32_t)(s * (NB * NLF) + b * NLF + f);
      uint32_t x0 = 0u, x1 = n;
      threefry2x32(0u, 42u, x0, x1);
      const uint32_t bits = x0 ^ x1;
      const float u = __uint_as_float((bits >> 9) | 0x3f800000u) - 1.0f;
      act = (u < p);
    } else {
      act = (p >= 0.5f);
    }
    if (act) mask |= (1u << s);
    terms[s] = act ? lp : l1p;
    out[OUT_ACT + (s * NB + b) * NLF + f] = act ? 1.0f : 0.0f;
  }
  actmask[b * NLF + f] = mask;

  // block-reduce logprob terms over f for each s
  __shared__ float red[NS][NLF];
#pragma unroll
  for (int s = 0; s < NS; ++s) red[s][f] = terms[s];
  __syncthreads();
  for (int off = 128; off > 0; off >>= 1) {
    if (f < off) {
#pragma unroll
      for (int s = 0; s < NS; ++s) red[s][f] += red[s][f + off];
    }
    __syncthreads();
  }
  if (f == 0) {
#pragma unroll
    for (int s = 0; s < NS; ++s) out[OUT_LOGP + s * NB + b] = red[s][0];
  }
}

// ---------- Kernel 3: values[s,b,v] ----------
// grid = (32, NB), 256 threads, one float4 per thread.
// CRITICAL: inner loops are BRANCHLESS (select via fminf with +/-INF from
// LDS) and loads are manually batched 8-deep so the compiler keeps 8
// global_load_dwordx4 in flight. Round-3 post-mortem: per-f `if` branches
// serialized loads (VGPR=24, 1 load in flight, 288 x 800ns = 231 us).
__global__ __launch_bounds__(256) void k_values(
    const float* __restrict__ q_logits,   // [B,LQ,V]
    const float* __restrict__ f_logits,   // [B,LF,V]
    const float* __restrict__ q_mask,     // [B,LQ]
    const unsigned* __restrict__ actmask, // ws [B,LF]
    float* __restrict__ out)              // d_out base (values at offset 0)
{
  const int b = blockIdx.y;
  const int tid = threadIdx.x;

  // ssel[s][f] = +INF if action s selects row f else -INF  (fminf select)
  __shared__ float ssel[NS][NLF];
  __shared__ float sqsel[NLQ];
  {
    const unsigned mk = actmask[b * NLF + tid];
#pragma unroll
    for (int s = 0; s < NS; ++s)
      ssel[s][tid] = (mk >> s) & 1u ? INFINITY : -INFINITY;
    if (tid < NLQ)
      sqsel[tid] = (q_mask[b * NLQ + tid] > 0.5f) ? INFINITY : -INFINITY;
  }
  __syncthreads();

  const int c4 = blockIdx.x * 256 + tid;      // float4 index within row
  if (c4 >= NV4) return;

  const float4* qp = (const float4*)q_logits;
  const float4* fp = (const float4*)f_logits;

  // ---- q part: raw masked max, log1p(relu(.)) applied ONCE at the end.
  // Valid because q_mask in {0,1}: masked-out terms contribute 0, and
  // log1p(relu(x)) >= 0 with log1p(relu(-INF -> relu 0)) = 0.
  float4 qm4 = make_float4(-INFINITY, -INFINITY, -INFINITY, -INFINITY);
#pragma unroll
  for (int l0 = 0; l0 < NLQ; l0 += 8) {
    float4 x[8];
#pragma unroll
    for (int j = 0; j < 8; ++j)
      x[j] = qp[(size_t)(b * NLQ + l0 + j) * NV4 + c4];
#pragma unroll
    for (int j = 0; j < 8; ++j) {
      const float sv = sqsel[l0 + j];
      qm4.x = fmaxf(qm4.x, fminf(x[j].x, sv));
      qm4.y = fmaxf(qm4.y, fminf(x[j].y, sv));
      qm4.z = fmaxf(qm4.z, fminf(x[j].z, sv));
      qm4.w = fmaxf(qm4.w, fminf(x[j].w, sv));
    }
  }
  const float q0 = log1pf(fmaxf(qm4.x, 0.f));
  const float q1 = log1pf(fmaxf(qm4.y, 0.f));
  const float q2 = log1pf(fmaxf(qm4.z, 0.f));
  const float q3 = log1pf(fmaxf(qm4.w, 0.f));

  // ---- f part: 4 masked raw maxes (one per sample), branchless.
  float m[NS][4];
#pragma unroll
  for (int s = 0; s < NS; ++s)
#pragma unroll
    for (int c = 0; c < 4; ++c) m[s][c] = -INFINITY;

  for (int f0 = 0; f0 < NLF; f0 += 8) {
    float4 x[8];
#pragma unroll
    for (int j = 0; j < 8; ++j)
      x[j] = fp[(size_t)(b * NLF + f0 + j) * NV4 + c4];
#pragma unroll
    for (int j = 0; j < 8; ++j) {
#pragma unroll
      for (int s = 0; s < NS; ++s) {
        const float sv = ssel[s][f0 + j];
        m[s][0] = fmaxf(m[s][0], fminf(x[j].x, sv));
        m[s][1] = fmaxf(m[s][1], fminf(x[j].y, sv));
        m[s][2] = fmaxf(m[s][2], fminf(x[j].z, sv));
        m[s][3] = fmaxf(m[s][3], fminf(x[j].w, sv));
      }
    }
  }

  float4* ov = (float4*)out;
#pragma unroll
  for (int s = 0; s < NS; ++s) {
    float4 r;
    r.x = fmaxf(q0, log1pf(fmaxf(m[s][0], 0.f)));
    r.y = fmaxf(q1, log1pf(fmaxf(m[s][1], 0.f)));
    r.z = fmaxf(q2, log1pf(fmaxf(m[s][2], 0.f)));
    r.w = fmaxf(q3, log1pf(fmaxf(m[s][3], 0.f)));
    ov[(size_t)(s * NB + b) * NV4 + c4] = r;
  }
}

extern "C" void kernel_launch(void* const* d_in, const int* in_sizes, int n_in,
                              void* d_out, int out_size, void* d_ws, size_t ws_size,
                              hipStream_t stream) {
  const float* attn_scores = (const float*)d_in[0];
  const float* q_logits    = (const float*)d_in[1];
  const float* f_logits    = (const float*)d_in[2];
  const float* q_mask      = (const float*)d_in[3];
  const float* attn_mask   = (const float*)d_in[4];
  float* out = (float*)d_out;

  float* ws_scores   = (float*)d_ws;                         // B*LQ*LF floats
  unsigned* ws_mask  = (unsigned*)(ws_scores + NB * NLQ * NLF); // B*LF uint32

  k_mean<<<dim3((NB * NLQ * NLF) / 256), 256, 0, stream>>>(attn_scores, ws_scores);
  k_probs<<<dim3(NB), 256, 0, stream>>>(ws_scores, attn_mask, out, ws_mask);
  k_values<<<dim3((NV4 + 255) / 256, NB), 256, 0, stream>>>(
      q_logits, f_logits, q_mask, ws_mask, out);
}